// Round 8
// baseline (391.525 us; speedup 1.0000x reference)
//
#include <hip/hip_runtime.h>

// AfmoeAttention on MI355X (gfx950), round 14.
// Diagnosis across r8/r12/r13 (all ~115us, MfmaUtil ~28%, conflicts 0,
// occupancy 17/27/24%): the invariant is LDS FRAGMENT-READ BYTES PER FLOP.
// 64x64-per-wave = 16 FLOP/B -> measured ~102 B/cy/CU = at the ds_read_b128
// pipe ceiling (m97's 912 TF works out to ~112 B/cy, same wall).
// Fix: per-wave 64x128 (acc[4][8]) -> 21.3 FLOP/B (0.75x LDS bytes), with
// r12's 72KB BK=32 tri-buffer footprint -> 2 blocks/CU = 2 waves/SIMD
// (fixes r9's 1-wave/SIMD failure; independent blocks de-sync barriers).
// 4 waves (256 thr), 128x256 tile; stage 6 loads/thread/tile, vmcnt(6) gate,
// raw barriers, setprio, BK32 swizzle phys = chunk ^ ((row>>1)&3).
// Epilogues: r9's harness-verified 2-heads-per-wave versions.
// gemm_out_k: same core, grid 32x8 = 256 blocks. attn + cvt unchanged.

#define LOG2E 1.44269504088896340736f

typedef __attribute__((ext_vector_type(4))) float f32x4;
typedef __attribute__((ext_vector_type(8))) short bf16x8;   // 8 x bf16 (4 VGPRs)

__device__ __forceinline__ float bf2f(unsigned short u) {
  union { unsigned u; float f; } x; x.u = ((unsigned)u) << 16; return x.f;
}
__device__ __forceinline__ unsigned short f2bf(float f) {
  union { float f; unsigned u; } x; x.f = f;
  unsigned r = x.u + 0x7fffu + ((x.u >> 16) & 1u);   // RNE
  return (unsigned short)(r >> 16);
}

// async global->LDS, 16B per lane. LDS dest = wave-uniform base + lane*16.
__device__ __forceinline__ void async16(void* lds, const void* g) {
  __builtin_amdgcn_global_load_lds(
      (const __attribute__((address_space(1))) unsigned*)g,
      (__attribute__((address_space(3))) unsigned*)lds, 16, 0, 0);
}
__device__ __forceinline__ void lds_fence() {
  __asm__ volatile("s_waitcnt lgkmcnt(0)" ::: "memory");
}

// ---------------------------------------------------------- fused cvt kernel
__global__ __launch_bounds__(256) void cvt_all(
    const float* __restrict__ s0, const float* __restrict__ s1,
    const float* __restrict__ s2, const float* __restrict__ s3,
    const float* __restrict__ s4, const float* __restrict__ s5,
    unsigned short* __restrict__ d0, unsigned short* __restrict__ d1,
    unsigned short* __restrict__ d2, unsigned short* __restrict__ d3,
    unsigned short* __restrict__ d4, unsigned short* __restrict__ d5) {
  const long total = 5505024;                       // f4 elements overall
  const long stride = (long)gridDim.x * 256;
  for (long i = (long)blockIdx.x * 256 + threadIdx.x; i < total; i += stride) {
    const float* s; unsigned short* d; long off;
    if      (i < 2097152) { s = s0; d = d0; off = 0; }
    else if (i < 3145728) { s = s1; d = d1; off = 2097152; }
    else if (i < 3276800) { s = s2; d = d2; off = 3145728; }
    else if (i < 3407872) { s = s3; d = d3; off = 3276800; }
    else if (i < 4456448) { s = s4; d = d4; off = 3407872; }
    else                  { s = s5; d = d5; off = 4456448; }
    long j = i - off;
    float4 v = reinterpret_cast<const float4*>(s)[j];
    ushort4 u;
    u.x = f2bf(v.x); u.y = f2bf(v.y); u.z = f2bf(v.z); u.w = f2bf(v.w);
    reinterpret_cast<ushort4*>(d)[j] = u;
  }
}

// ------------------------------- 128x256 core, 4 waves, per-wave 64x128
// BK=32. Wave w: rows (w&1)*64, cols (w>>1)*128 -> acc[4][8] 16x16 frags.
// Per iter per wave: 12 frag ds_read_b128 (4 A + 8 B) feed 32 MFMAs
// (21.3 FLOP per LDS byte vs 16 for the 64x64 shape -> 0.75x LDS traffic).
// LDS row = 32 bf16 = 4 chunks of 16B; logical chunk c of row r at phys
// c ^ ((r>>1)&3); staging pre-swizzles the GLOBAL source chunk.
// LDS: A 3x4096 elems @0, B 3x8192 elems @12288 = 72KB -> 2 blocks/CU
// (= 2 waves/SIMD; independent blocks de-sync their barrier phases).
// Iter t computes tile t from buf[t%3], stages tile t+2 (A 2 + B 4 loads).
// Gate vmcnt(6): t+1's 6 loads landed, t+2's 6 stay in flight.
__device__ __forceinline__ void gemm_core(
    const unsigned short* __restrict__ A, const unsigned short* __restrict__ W,
    int m0, int n0, unsigned short* lds, f32x4 acc[4][8]) {
  const int tid = threadIdx.x;              // 0..255
  const int w = tid >> 6, l = tid & 63, quad = l >> 4, l16 = l & 15;
  const int wm = (w & 1) * 64, wn = (w >> 1) * 128;
  const int rlo = tid >> 2, ch = tid & 3;   // stage: row 0..63, chunk 0..3

  const f32x4 Z4 = {0.f, 0.f, 0.f, 0.f};
#pragma unroll
  for (int i = 0; i < 4; i++)
#pragma unroll
    for (int j = 0; j < 8; j++) acc[i][j] = Z4;

  // staging sources, pre-swizzled chunk; row passes +64 keep (r>>1)&3.
  const unsigned short* gA =
      A + (size_t)(m0 + rlo) * 2048 + ((ch ^ ((rlo >> 1) & 3)) * 8);
  const unsigned short* gB =
      W + (size_t)(n0 + rlo) * 2048 + ((ch ^ ((rlo >> 1) & 3)) * 8);

  int arow[4], brow[8];
#pragma unroll
  for (int mt = 0; mt < 4; mt++) arow[mt] = (wm + mt * 16 + l16) * 32;
#pragma unroll
  for (int nt = 0; nt < 8; nt++) brow[nt] = (wn + nt * 16 + l16) * 32;
  const int fx = (quad ^ ((l16 >> 1) & 3)) * 8;

  unsigned short* const bA = lds;           // 3 x 4096 elems (A: 128x32)
  unsigned short* const bB = lds + 12288;   // 3 x 8192 elems (B: 256x32)

  // ---- prologue: stage tiles 0,1 -> bufs 0,1 (6 loads/thread each)
#pragma unroll
  for (int tt = 0; tt < 2; ++tt) {
    const int ko = tt * 32;
    async16(bA + tt * 4096 + tid * 8,        gA + ko);
    async16(bA + tt * 4096 + 2048 + tid * 8, gA + 131072 + ko);
    async16(bB + tt * 8192 + tid * 8,        gB + ko);
    async16(bB + tt * 8192 + 2048 + tid * 8, gB + 131072 + ko);
    async16(bB + tt * 8192 + 4096 + tid * 8, gB + 262144 + ko);
    async16(bB + tt * 8192 + 6144 + tid * 8, gB + 393216 + ko);
  }
  __asm__ volatile("s_waitcnt vmcnt(6)" ::: "memory");   // tile 0 landed
  __builtin_amdgcn_s_barrier();

  int cb = 0;
  for (int t = 0; t < 64; ++t) {
    unsigned short* cA = bA + cb * 4096;
    unsigned short* cB = bB + cb * 8192;

    if (t < 62) {                           // stage tile t+2 (6 loads)
      int nb = cb + 2; if (nb >= 3) nb -= 3;
      const int ko = (t + 2) * 32;
      async16(bA + nb * 4096 + tid * 8,        gA + ko);
      async16(bA + nb * 4096 + 2048 + tid * 8, gA + 131072 + ko);
      async16(bB + nb * 8192 + tid * 8,        gB + ko);
      async16(bB + nb * 8192 + 2048 + tid * 8, gB + 131072 + ko);
      async16(bB + nb * 8192 + 4096 + tid * 8, gB + 262144 + ko);
      async16(bB + nb * 8192 + 6144 + tid * 8, gB + 393216 + ko);
    }
    bf16x8 af[4], bf[8];
#pragma unroll
    for (int mt = 0; mt < 4; mt++)
      af[mt] = *(const bf16x8*)&cA[arow[mt] + fx];
#pragma unroll
    for (int nt = 0; nt < 8; nt++)
      bf[nt] = *(const bf16x8*)&cB[brow[nt] + fx];
    __builtin_amdgcn_s_barrier();
    __asm__ volatile("s_waitcnt lgkmcnt(0)" ::: "memory");
    __builtin_amdgcn_sched_barrier(0);
    __builtin_amdgcn_s_setprio(1);
#pragma unroll
    for (int mt = 0; mt < 4; mt++)
#pragma unroll
      for (int nt = 0; nt < 8; nt++)
        acc[mt][nt] = __builtin_amdgcn_mfma_f32_16x16x32_bf16(
            af[mt], bf[nt], acc[mt][nt], 0, 0, 0);
    __builtin_amdgcn_s_setprio(0);
    if (t < 62) {
      __asm__ volatile("s_waitcnt vmcnt(6)" ::: "memory");  // t+1 landed
    } else if (t == 62) {
      __asm__ volatile("s_waitcnt vmcnt(0)" ::: "memory");  // tail drain (once)
    }
    __builtin_amdgcn_s_barrier();
    cb++; if (cb == 3) cb = 0;
  }
}

// --------------------------------------- fused QKVG GEMM + RMSNorm/RoPE/T
// N-space = [Q 2048 | K 256 | V 256 | G 2048] in 256-col tiles (ny 0..17).
// ny 0..7 : Q -> RMSNorm+RoPE, scale 1/8 | ny==8 : K -> RMSNorm+RoPE, LOG2E
// ny == 9 : V -> transpose-scatter       | ny 10..17: G -> bf16 store.
// Each wave spans 128 cols = TWO heads (nt 0..3 head hb0, nt 4..7 hb0+1).
__global__ __launch_bounds__(256, 2) void gemm_qkvg(
    const unsigned short* __restrict__ X,
    const unsigned short* __restrict__ Wq, const unsigned short* __restrict__ Wk,
    const unsigned short* __restrict__ Wv, const unsigned short* __restrict__ Wg,
    const float* __restrict__ cosb, const float* __restrict__ sinb,
    const float* __restrict__ qg, const float* __restrict__ kg,
    unsigned short* __restrict__ Qn, unsigned short* __restrict__ Kn,
    unsigned short* __restrict__ Vt, unsigned short* __restrict__ gate) {
  __shared__ __attribute__((aligned(16))) unsigned short lds[36864];  // 72 KB
  const int ny = blockIdx.y;
  const unsigned short* W; int n0, type;
  if (ny < 8)       { W = Wq; n0 = ny * 256;        type = 0; }
  else if (ny == 8) { W = Wk; n0 = 0;               type = 1; }
  else if (ny == 9) { W = Wv; n0 = 0;               type = 2; }
  else              { W = Wg; n0 = (ny - 10) * 256; type = 3; }
  const int m0 = blockIdx.x * 128;

  f32x4 acc[4][8];
  gemm_core(X, W, m0, n0, lds, acc);

  const int tid = threadIdx.x;
  const int w = tid >> 6, l = tid & 63, quad = l >> 4, l16 = l & 15;
  const int wm = (w & 1) * 64, wn = (w >> 1) * 128;

  if (type == 3) {          // gate: plain bf16 store
#pragma unroll
    for (int mt = 0; mt < 4; mt++)
#pragma unroll
      for (int r = 0; r < 4; r++) {
        int row = m0 + wm + mt * 16 + quad * 4 + r;
#pragma unroll
        for (int nt = 0; nt < 8; nt++)
          gate[(size_t)row * 2048 + n0 + wn + nt * 16 + l16] =
              f2bf(acc[mt][nt][r]);
      }
    return;
  }
  if (type == 2) {          // V: transpose-scatter to Vt[b][kv][d][s]
#pragma unroll
    for (int mt = 0; mt < 4; mt++)
#pragma unroll
      for (int r = 0; r < 4; r++) {
        int row = m0 + wm + mt * 16 + quad * 4 + r;
        int b = row >> 11, s = row & 2047;
#pragma unroll
        for (int nt = 0; nt < 8; nt++) {
          int col = wn + nt * 16 + l16;
          int kvh = col >> 6, d = col & 63;
          Vt[((size_t)(b * 4 + kvh) * 64 + d) * 2048 + s] =
              f2bf(acc[mt][nt][r]);
        }
      }
    return;
  }

  // Q/K: RMSNorm (f32 acc) + RoPE + scale, transposed store. Two heads/wave.
  const float* gamma = (type == 0) ? qg : kg;
  const float scale  = (type == 0) ? 0.125f : LOG2E;
  const int hb0 = (n0 + wn) >> 6;    // first head of this wave's 128-col span
  float gv[8];
#pragma unroll
  for (int nt = 0; nt < 8; nt++) gv[nt] = gamma[(nt & 3) * 16 + l16];

#pragma unroll
  for (int mt = 0; mt < 4; mt++)
#pragma unroll
    for (int r = 0; r < 4; r++) {
      int row = m0 + wm + mt * 16 + quad * 4 + r;
      float ss0 = 0.f, ss1 = 0.f;
#pragma unroll
      for (int nt = 0; nt < 4; nt++) {
        float v = acc[mt][nt][r]; ss0 += v * v;
      }
#pragma unroll
      for (int nt = 4; nt < 8; nt++) {
        float v = acc[mt][nt][r]; ss1 += v * v;
      }
#pragma unroll
      for (int off = 1; off < 16; off <<= 1) {
        ss0 += __shfl_xor(ss0, off);
        ss1 += __shfl_xor(ss1, off);
      }
      float rr0 = rsqrtf(ss0 * (1.0f / 64.0f) + 1e-6f);
      float rr1 = rsqrtf(ss1 * (1.0f / 64.0f) + 1e-6f);
      float xn[8];
#pragma unroll
      for (int nt = 0; nt < 8; nt++)
        xn[nt] = acc[mt][nt][r] * ((nt < 4) ? rr0 : rr1) * gv[nt];
      int b = row >> 11, s = row & 2047;
      unsigned short* dst0 = (type == 0)
          ? Qn + ((size_t)(b * 32 + hb0) * 2048 + s) * 64
          : Kn + ((size_t)(b * 4 + hb0) * 2048 + s) * 64;
      unsigned short* dst1 = (type == 0)
          ? Qn + ((size_t)(b * 32 + hb0 + 1) * 2048 + s) * 64
          : Kn + ((size_t)(b * 4 + hb0 + 1) * 2048 + s) * 64;
#pragma unroll
      for (int nt = 0; nt < 8; nt++) {
        int d = (nt & 3) * 16 + l16;
        float rot = ((nt & 3) < 2) ? -xn[nt ^ 2] : xn[nt ^ 2];
        float cv = cosb[(size_t)row * 64 + d];
        float sv = sinb[(size_t)row * 64 + d];
        float val = (xn[nt] * cv + rot * sv) * scale;
        ((nt < 4) ? dst0 : dst1)[d] = f2bf(val);
      }
    }
}

// -------------------------------------------------------------- output GEMM
// grid 32 x 8 = 256 blocks; 2-blocks/CU capacity lets the scheduler spread
// them 1/CU (or pack when convenient).
__global__ __launch_bounds__(256, 2) void gemm_out_k(
    const unsigned short* __restrict__ A, const unsigned short* __restrict__ W,
    float* __restrict__ C) {
  __shared__ __attribute__((aligned(16))) unsigned short lds[36864];  // 72 KB
  const int m0 = blockIdx.x * 128, n0 = blockIdx.y * 256;
  f32x4 acc[4][8];
  gemm_core(A, W, m0, n0, lds, acc);
  const int tid = threadIdx.x;
  const int w = tid >> 6, l = tid & 63, quad = l >> 4, l16 = l & 15;
  const int wm = (w & 1) * 64, wn = (w >> 1) * 128;
#pragma unroll
  for (int mt = 0; mt < 4; mt++)
#pragma unroll
    for (int nt = 0; nt < 8; nt++) {
      int row = m0 + wm + mt * 16 + quad * 4;
      int col = n0 + wn + nt * 16 + l16;
#pragma unroll
      for (int r = 0; r < 4; r++)
        C[(size_t)(row + r) * 2048 + col] = acc[mt][nt][r];
    }
}

// ---------------------------------------------------------- flash attention
// (unchanged from r10: r6 structure + setprio around MFMA clusters)
__global__ __launch_bounds__(256, 4) void attn(
    const unsigned short* __restrict__ Qn, const unsigned short* __restrict__ Kn,
    const unsigned short* __restrict__ Vt, const unsigned short* __restrict__ gate,
    unsigned short* __restrict__ act) {
  __shared__ __attribute__((aligned(16))) unsigned short smem[20480];  // 40 KB
  unsigned short* Ps = smem + 16384;    // 4 x [32 q][32 kv] = 8 KB

  const int tid = threadIdx.x, w = tid >> 6, l = tid & 63;
  const int quad = l >> 4, l16 = l & 15, l7 = l16 & 7;
  const int bh = blockIdx.y, b = bh >> 5, h = bh & 31, kvh = h >> 3;
  const int q0 = blockIdx.x * 128;

  const unsigned short* Qg = Qn + ((size_t)(b * 32 + h) * 2048 + q0) * 64;
  const unsigned short* Kg = Kn + (size_t)(b * 4 + kvh) * 2048 * 64;
  const unsigned short* Vg = Vt + (size_t)(b * 4 + kvh) * 64 * 2048;
  unsigned short* Pw = Ps + w * 1024;   // wave-private [32 q][32 kv]

  const int kq_src = ((tid & 7) ^ ((tid >> 3) & 7)) * 8;

  // ---- prologue: stage Q [128][64] into smem[0..8192), read q-fragments
#pragma unroll
  for (int i = 0; i < 4; i++)
    async16(smem + i * 2048 + tid * 8,
            Qg + (size_t)(i * 32 + (tid >> 3)) * 64 + kq_src);
  __syncthreads();
  bf16x8 qf[2][2];
#pragma unroll
  for (int mt = 0; mt < 2; mt++)
#pragma unroll
    for (int ks = 0; ks < 2; ks++) {
      int row = w * 32 + mt * 16 + l16;           // row&7 == l7
      qf[mt][ks] = *(const bf16x8*)&smem[row * 64 + ((ks * 4 + quad) ^ l7) * 8];
    }
  __syncthreads();   // Q region free for K/V staging

  const f32x4 Z4 = {0.f, 0.f, 0.f, 0.f};
  f32x4 O[2][4];
  float lp[2][4];
#pragma unroll
  for (int mt = 0; mt < 2; mt++) {
#pragma unroll
    for (int nt = 0; nt < 4; nt++) O[mt][nt] = Z4;
#pragma unroll
    for (int r = 0; r < 4; r++) lp[mt][r] = 0.f;
  }

  // stage tile 0 into buf0
#pragma unroll
  for (int i = 0; i < 2; i++) {
    async16(smem + i * 2048 + tid * 8,
            Kg + (size_t)(i * 32 + (tid >> 3)) * 64 + kq_src);
    async16(smem + 4096 + i * 2048 + tid * 8,
            Vg + (size_t)(i * 32 + (tid >> 3)) * 2048 + kq_src);
  }

  for (int kt = 0; kt < 32; kt++) {
    __syncthreads();   // drains stage(kt); all waves past compute(kt-1)

    if (kt < 31) {     // stage tile kt+1 into the other buffer (overlapped)
      unsigned short* nb = smem + ((kt + 1) & 1) * 8192;
      const int s1 = (kt + 1) * 64;
#pragma unroll
      for (int i = 0; i < 2; i++) {
        async16(nb + i * 2048 + tid * 8,
                Kg + (size_t)(s1 + i * 32 + (tid >> 3)) * 64 + kq_src);
        async16(nb + 4096 + i * 2048 + tid * 8,
                Vg + (size_t)(i * 32 + (tid >> 3)) * 2048 + s1 + kq_src);
      }
    }

    unsigned short* Ks  = smem + (kt & 1) * 8192;
    unsigned short* Vts = Ks + 4096;

    // ---- S = Q K^T over this kv-64 tile
    f32x4 sc[2][4];
#pragma unroll
    for (int mt = 0; mt < 2; mt++)
#pragma unroll
      for (int nt = 0; nt < 4; nt++) sc[mt][nt] = Z4;
    __builtin_amdgcn_s_setprio(1);
#pragma unroll
    for (int nt = 0; nt < 4; nt++) {
      int row = nt * 16 + l16;                    // row&7 == l7
      bf16x8 kf0 = *(const bf16x8*)&Ks[row * 64 + (quad ^ l7) * 8];
      bf16x8 kf1 = *(const bf16x8*)&Ks[row * 64 + ((4 + quad) ^ l7) * 8];
#pragma unroll
      for (int mt = 0; mt < 2; mt++) {
        sc[mt][nt] = __builtin_amdgcn_mfma_f32_16x16x32_bf16(qf[mt][0], kf0, sc[mt][nt], 0, 0, 0);
        sc[mt][nt] = __builtin_amdgcn_mfma_f32_16x16x32_bf16(qf[mt][1], kf1, sc[mt][nt], 0, 0, 0);
      }
    }
    __builtin_amdgcn_s_setprio(0);

    // ---- softmax + PV in two kv-32 sub-chunks through wave-private Ps
#pragma unroll
    for (int ks2 = 0; ks2 < 2; ks2++) {
#pragma unroll
      for (int mt = 0; mt < 2; mt++)
#pragma unroll
        for (int ntl = 0; ntl < 2; ntl++) {
          int nt = ks2 * 2 + ntl;
#pragma unroll
          for (int r = 0; r < 4; r++) {
            float p = __builtin_amdgcn_exp2f(sc[mt][nt][r]);
            union { float f; unsigned u; } x; x.f = p;
            union { unsigned u; float f; } t; t.u = x.u & 0xffff0000u;
            lp[mt][r] += t.f;
            int q = mt * 16 + quad * 4 + r;
            int c = ntl * 2 + (l16 >> 3);
            int phys = c ^ ((q >> 1) & 3);
            Pw[q * 32 + phys * 8 + l7] = (unsigned short)(x.u >> 16);
          }
        }
      lds_fence();   // P writes visible before reads (same wave)

      bf16x8 pf[2];
#pragma unroll
      for (int mt = 0; mt < 2; mt++) {
        int q = mt * 16 + l16;
        int phys = quad ^ ((l16 >> 1) & 3);
        pf[mt] = *(const bf16x8*)&Pw[q * 32 + phys * 8];
      }
      __builtin_amdgcn_s_setprio(1);
#pragma unroll
      for (int nt2 = 0; nt2 < 4; nt2++) {
        int d = nt2 * 16 + l16;                   // d&7 == l7
        bf16x8 vf = *(const bf16x8*)&Vts[d * 64 + ((ks2 * 4 + quad) ^ l7) * 8];
#pragma unroll
        for (int mt = 0; mt < 2; mt++)
          O[mt][nt2] = __builtin_amdgcn_mfma_f32_16x16x32_bf16(
              pf[mt], vf, O[mt][nt2], 0, 0, 0);
      }
      __builtin_amdgcn_s_setprio(0);
      lds_fence();   // sub-chunk reads retired before next sub-chunk writes
    }
  }

  // ---- final l reduction across the 16-lane column groups (once)
#pragma unroll
  for (int mt = 0; mt < 2; mt++)
#pragma unroll
    for (int r = 0; r < 4; r++) {
      float s = lp[mt][r];
#pragma unroll
      for (int off = 1; off < 16; off <<= 1) s += __shfl_xor(s, off);
      lp[mt][r] = s;
    }

  // ---- epilogue: O/l * sigmoid(gate) -> act[b][s][h*64+d]
#pragma unroll
  for (int mt = 0; mt < 2; mt++) {
    float inv[4];
#pragma unroll
    for (int r = 0; r < 4; r++) inv[r] = 1.0f / lp[mt][r];
#pragma unroll
    for (int nt = 0; nt < 4; nt++)
#pragma unroll
      for (int r = 0; r < 4; r++) {
        int srow = q0 + w * 32 + mt * 16 + quad * 4 + r;
        int col = h * 64 + nt * 16 + l16;
        size_t off = (size_t)(b * 2048 + srow) * 2048 + col;
        float g = bf2f(gate[off]);
        float sig = 1.0f / (1.0f + __builtin_amdgcn_exp2f(-g * LOG2E));
        act[off] = f2bf(O[mt][nt][r] * inv[r] * sig);
      }
  }
}

// ------------------------------------------------------------------ launcher
extern "C" void kernel_launch(void* const* d_in, const int* in_sizes, int n_in,
                              void* d_out, int out_size, void* d_ws, size_t ws_size,
                              hipStream_t stream) {
  const float* hid  = (const float*)d_in[0];
  const float* cosb = (const float*)d_in[1];
  const float* sinb = (const float*)d_in[2];
  const float* Wq   = (const float*)d_in[3];
  const float* Wk   = (const float*)d_in[4];
  const float* Wv   = (const float*)d_in[5];
  const float* Wg   = (const float*)d_in[6];
  const float* Wo   = (const float*)d_in[7];
  const float* qg   = (const float*)d_in[8];
  const float* kg   = (const float*)d_in[9];
  float* out = (float*)d_out;

  char* ws = (char*)d_ws;
  unsigned short* Xb   = (unsigned short*)(ws);              // 16,777,216 B
  unsigned short* WqB  = (unsigned short*)(ws + 16777216);   //  8,388,608
  unsigned short* WkB  = (unsigned short*)(ws + 25165824);   //  1,048,576
  unsigned short* WvB  = (unsigned short*)(ws + 26214400);   //  1,048,576
  unsigned short* WgB  = (unsigned short*)(ws + 27262976);   //  8,388,608
  unsigned short* WoB  = (unsigned short*)(ws + 35651584);   //  8,388,608
  unsigned short* gate = (unsigned short*)(ws + 44040192);   // 16,777,216
  unsigned short* Qn   = (unsigned short*)(ws + 60817408);   // 16,777,216
  unsigned short* Kn   = (unsigned short*)(ws + 77594624);   //  2,097,152
  unsigned short* Vt   = (unsigned short*)(ws + 79691776);   //  2,097,152
  // region reuse: act overlays WqB..WgB (18 MB, dead after gemm_qkvg)
  unsigned short* act = WqB;

  cvt_all<<<dim3(2048), dim3(256), 0, stream>>>(
      hid, Wq, Wk, Wv, Wg, Wo, Xb, WqB, WkB, WvB, WgB, WoB);

  gemm_qkvg<<<dim3(32, 18), dim3(256), 0, stream>>>(
      Xb, WqB, WkB, WvB, WgB, cosb, sinb, qg, kg, Qn, Kn, Vt, gate);

  attn<<<dim3(16, 64), dim3(256), 0, stream>>>(Qn, Kn, Vt, gate, act);

  gemm_out_k<<<dim3(32, 8), dim3(256), 0, stream>>>(act, WoB, out);
}

// Round 9
// 382.339 us; speedup vs baseline: 1.0240x; 1.0240x over previous
//
#include <hip/hip_runtime.h>

// AfmoeAttention on MI355X (gfx950), round 15.
// Post-mortem r8-r14: FIVE geometries all ~113-116us, MfmaUtil ~28%,
// conflicts 0, occupancy 14-27% -> the invariant is the LOOP STRUCTURE:
// a mid s_barrier + lgkmcnt(0) + sched_barrier(0) between frag reads and
// MFMAs serializes read-latency and matrix work every iteration in every
// geometry. m97 (SAME geometry as r13: 128sq, 4 waves, BK32) hits 912 TF
// vs our 672 with reads+MFMAs in ONE barrier section (compiler emits
// counted lgkmcnt(4/3/1/0) so reads hide under MFMAs).
// r15 = r14 with the gemm_core loop de-fenced:
//   stage-issue -> frag reads -> setprio MFMAs (nt-outer) -> vmcnt(6) -> barrier
// No mid-barrier, no explicit lgkm drain, no sched pin: the compiler's
// automatic per-operand lgkmcnt waits do the fine-grained interleave.
// Correctness: reads/stages can't cross the "memory" vmcnt asm; the end
// barrier still protects buffer overwrite (tri-buffer: stage(t+3) issues
// only after all waves passed end-of-iter-t barrier).
// attn + cvt_all unchanged (isolate the experiment).

#define LOG2E 1.44269504088896340736f

typedef __attribute__((ext_vector_type(4))) float f32x4;
typedef __attribute__((ext_vector_type(8))) short bf16x8;   // 8 x bf16 (4 VGPRs)

__device__ __forceinline__ float bf2f(unsigned short u) {
  union { unsigned u; float f; } x; x.u = ((unsigned)u) << 16; return x.f;
}
__device__ __forceinline__ unsigned short f2bf(float f) {
  union { float f; unsigned u; } x; x.f = f;
  unsigned r = x.u + 0x7fffu + ((x.u >> 16) & 1u);   // RNE
  return (unsigned short)(r >> 16);
}

// async global->LDS, 16B per lane. LDS dest = wave-uniform base + lane*16.
__device__ __forceinline__ void async16(void* lds, const void* g) {
  __builtin_amdgcn_global_load_lds(
      (const __attribute__((address_space(1))) unsigned*)g,
      (__attribute__((address_space(3))) unsigned*)lds, 16, 0, 0);
}
__device__ __forceinline__ void lds_fence() {
  __asm__ volatile("s_waitcnt lgkmcnt(0)" ::: "memory");
}

// ---------------------------------------------------------- fused cvt kernel
__global__ __launch_bounds__(256) void cvt_all(
    const float* __restrict__ s0, const float* __restrict__ s1,
    const float* __restrict__ s2, const float* __restrict__ s3,
    const float* __restrict__ s4, const float* __restrict__ s5,
    unsigned short* __restrict__ d0, unsigned short* __restrict__ d1,
    unsigned short* __restrict__ d2, unsigned short* __restrict__ d3,
    unsigned short* __restrict__ d4, unsigned short* __restrict__ d5) {
  const long total = 5505024;                       // f4 elements overall
  const long stride = (long)gridDim.x * 256;
  for (long i = (long)blockIdx.x * 256 + threadIdx.x; i < total; i += stride) {
    const float* s; unsigned short* d; long off;
    if      (i < 2097152) { s = s0; d = d0; off = 0; }
    else if (i < 3145728) { s = s1; d = d1; off = 2097152; }
    else if (i < 3276800) { s = s2; d = d2; off = 3145728; }
    else if (i < 3407872) { s = s3; d = d3; off = 3276800; }
    else if (i < 4456448) { s = s4; d = d4; off = 3407872; }
    else                  { s = s5; d = d5; off = 4456448; }
    long j = i - off;
    float4 v = reinterpret_cast<const float4*>(s)[j];
    ushort4 u;
    u.x = f2bf(v.x); u.y = f2bf(v.y); u.z = f2bf(v.z); u.w = f2bf(v.w);
    reinterpret_cast<ushort4*>(d)[j] = u;
  }
}

// ------------------------------- 128x256 core, 4 waves, per-wave 64x128
// BK=32. Wave w: rows (w&1)*64, cols (w>>1)*128 -> acc[4][8] 16x16 frags.
// LDS row = 32 bf16 = 4 chunks of 16B; logical chunk c of row r at phys
// c ^ ((r>>1)&3); staging pre-swizzles the GLOBAL source chunk.
// LDS: A 3x4096 elems @0, B 3x8192 elems @12288 = 72KB -> 2 blocks/CU.
// Iter t: stage t+2 (6 loads), frag reads + MFMAs in ONE section (compiler
// interleaves with counted lgkmcnt), vmcnt(6) gate (t+1 landed, t+2 in
// flight), single barrier (protects buf[t] from stage(t+3) overwrite).
__device__ __forceinline__ void gemm_core(
    const unsigned short* __restrict__ A, const unsigned short* __restrict__ W,
    int m0, int n0, unsigned short* lds, f32x4 acc[4][8]) {
  const int tid = threadIdx.x;              // 0..255
  const int w = tid >> 6, l = tid & 63, quad = l >> 4, l16 = l & 15;
  const int wm = (w & 1) * 64, wn = (w >> 1) * 128;
  const int rlo = tid >> 2, ch = tid & 3;   // stage: row 0..63, chunk 0..3

  const f32x4 Z4 = {0.f, 0.f, 0.f, 0.f};
#pragma unroll
  for (int i = 0; i < 4; i++)
#pragma unroll
    for (int j = 0; j < 8; j++) acc[i][j] = Z4;

  // staging sources, pre-swizzled chunk; row passes +64 keep (r>>1)&3.
  const unsigned short* gA =
      A + (size_t)(m0 + rlo) * 2048 + ((ch ^ ((rlo >> 1) & 3)) * 8);
  const unsigned short* gB =
      W + (size_t)(n0 + rlo) * 2048 + ((ch ^ ((rlo >> 1) & 3)) * 8);

  int arow[4], brow[8];
#pragma unroll
  for (int mt = 0; mt < 4; mt++) arow[mt] = (wm + mt * 16 + l16) * 32;
#pragma unroll
  for (int nt = 0; nt < 8; nt++) brow[nt] = (wn + nt * 16 + l16) * 32;
  const int fx = (quad ^ ((l16 >> 1) & 3)) * 8;

  unsigned short* const bA = lds;           // 3 x 4096 elems (A: 128x32)
  unsigned short* const bB = lds + 12288;   // 3 x 8192 elems (B: 256x32)

  // ---- prologue: stage tiles 0,1 -> bufs 0,1 (6 loads/thread each)
#pragma unroll
  for (int tt = 0; tt < 2; ++tt) {
    const int ko = tt * 32;
    async16(bA + tt * 4096 + tid * 8,        gA + ko);
    async16(bA + tt * 4096 + 2048 + tid * 8, gA + 131072 + ko);
    async16(bB + tt * 8192 + tid * 8,        gB + ko);
    async16(bB + tt * 8192 + 2048 + tid * 8, gB + 131072 + ko);
    async16(bB + tt * 8192 + 4096 + tid * 8, gB + 262144 + ko);
    async16(bB + tt * 8192 + 6144 + tid * 8, gB + 393216 + ko);
  }
  __asm__ volatile("s_waitcnt vmcnt(6)" ::: "memory");   // tile 0 landed
  __builtin_amdgcn_s_barrier();

  int cb = 0;
  for (int t = 0; t < 64; ++t) {
    unsigned short* cA = bA + cb * 4096;
    unsigned short* cB = bB + cb * 8192;

    if (t < 62) {                           // stage tile t+2 (6 loads)
      int nb = cb + 2; if (nb >= 3) nb -= 3;
      const int ko = (t + 2) * 32;
      async16(bA + nb * 4096 + tid * 8,        gA + ko);
      async16(bA + nb * 4096 + 2048 + tid * 8, gA + 131072 + ko);
      async16(bB + nb * 8192 + tid * 8,        gB + ko);
      async16(bB + nb * 8192 + 2048 + tid * 8, gB + 131072 + ko);
      async16(bB + nb * 8192 + 4096 + tid * 8, gB + 262144 + ko);
      async16(bB + nb * 8192 + 6144 + tid * 8, gB + 393216 + ko);
    }

    // frag reads + MFMAs in one section: the compiler inserts per-operand
    // counted lgkmcnt waits, hiding read latency under MFMA columns.
    bf16x8 af[4], bf[8];
#pragma unroll
    for (int mt = 0; mt < 4; mt++)
      af[mt] = *(const bf16x8*)&cA[arow[mt] + fx];
#pragma unroll
    for (int nt = 0; nt < 8; nt++)
      bf[nt] = *(const bf16x8*)&cB[brow[nt] + fx];

    __builtin_amdgcn_s_setprio(1);
#pragma unroll
    for (int nt = 0; nt < 8; nt++)          // nt-outer: natural wait ladder
#pragma unroll
      for (int mt = 0; mt < 4; mt++)
        acc[mt][nt] = __builtin_amdgcn_mfma_f32_16x16x32_bf16(
            af[mt], bf[nt], acc[mt][nt], 0, 0, 0);
    __builtin_amdgcn_s_setprio(0);

    if (t < 62) {
      __asm__ volatile("s_waitcnt vmcnt(6)" ::: "memory");  // t+1 landed
    } else if (t == 62) {
      __asm__ volatile("s_waitcnt vmcnt(0)" ::: "memory");  // tail drain (once)
    }
    __builtin_amdgcn_s_barrier();           // buf[t] reads done block-wide
    cb++; if (cb == 3) cb = 0;
  }
}

// --------------------------------------- fused QKVG GEMM + RMSNorm/RoPE/T
// N-space = [Q 2048 | K 256 | V 256 | G 2048] in 256-col tiles (ny 0..17).
// ny 0..7 : Q -> RMSNorm+RoPE, scale 1/8 | ny==8 : K -> RMSNorm+RoPE, LOG2E
// ny == 9 : V -> transpose-scatter       | ny 10..17: G -> bf16 store.
// Each wave spans 128 cols = TWO heads (nt 0..3 head hb0, nt 4..7 hb0+1).
__global__ __launch_bounds__(256, 2) void gemm_qkvg(
    const unsigned short* __restrict__ X,
    const unsigned short* __restrict__ Wq, const unsigned short* __restrict__ Wk,
    const unsigned short* __restrict__ Wv, const unsigned short* __restrict__ Wg,
    const float* __restrict__ cosb, const float* __restrict__ sinb,
    const float* __restrict__ qg, const float* __restrict__ kg,
    unsigned short* __restrict__ Qn, unsigned short* __restrict__ Kn,
    unsigned short* __restrict__ Vt, unsigned short* __restrict__ gate) {
  __shared__ __attribute__((aligned(16))) unsigned short lds[36864];  // 72 KB
  const int ny = blockIdx.y;
  const unsigned short* W; int n0, type;
  if (ny < 8)       { W = Wq; n0 = ny * 256;        type = 0; }
  else if (ny == 8) { W = Wk; n0 = 0;               type = 1; }
  else if (ny == 9) { W = Wv; n0 = 0;               type = 2; }
  else              { W = Wg; n0 = (ny - 10) * 256; type = 3; }
  const int m0 = blockIdx.x * 128;

  f32x4 acc[4][8];
  gemm_core(X, W, m0, n0, lds, acc);

  const int tid = threadIdx.x;
  const int w = tid >> 6, l = tid & 63, quad = l >> 4, l16 = l & 15;
  const int wm = (w & 1) * 64, wn = (w >> 1) * 128;

  if (type == 3) {          // gate: plain bf16 store
#pragma unroll
    for (int mt = 0; mt < 4; mt++)
#pragma unroll
      for (int r = 0; r < 4; r++) {
        int row = m0 + wm + mt * 16 + quad * 4 + r;
#pragma unroll
        for (int nt = 0; nt < 8; nt++)
          gate[(size_t)row * 2048 + n0 + wn + nt * 16 + l16] =
              f2bf(acc[mt][nt][r]);
      }
    return;
  }
  if (type == 2) {          // V: transpose-scatter to Vt[b][kv][d][s]
#pragma unroll
    for (int mt = 0; mt < 4; mt++)
#pragma unroll
      for (int r = 0; r < 4; r++) {
        int row = m0 + wm + mt * 16 + quad * 4 + r;
        int b = row >> 11, s = row & 2047;
#pragma unroll
        for (int nt = 0; nt < 8; nt++) {
          int col = wn + nt * 16 + l16;
          int kvh = col >> 6, d = col & 63;
          Vt[((size_t)(b * 4 + kvh) * 64 + d) * 2048 + s] =
              f2bf(acc[mt][nt][r]);
        }
      }
    return;
  }

  // Q/K: RMSNorm (f32 acc) + RoPE + scale, transposed store. Two heads/wave.
  const float* gamma = (type == 0) ? qg : kg;
  const float scale  = (type == 0) ? 0.125f : LOG2E;
  const int hb0 = (n0 + wn) >> 6;    // first head of this wave's 128-col span
  float gv[8];
#pragma unroll
  for (int nt = 0; nt < 8; nt++) gv[nt] = gamma[(nt & 3) * 16 + l16];

#pragma unroll
  for (int mt = 0; mt < 4; mt++)
#pragma unroll
    for (int r = 0; r < 4; r++) {
      int row = m0 + wm + mt * 16 + quad * 4 + r;
      float ss0 = 0.f, ss1 = 0.f;
#pragma unroll
      for (int nt = 0; nt < 4; nt++) {
        float v = acc[mt][nt][r]; ss0 += v * v;
      }
#pragma unroll
      for (int nt = 4; nt < 8; nt++) {
        float v = acc[mt][nt][r]; ss1 += v * v;
      }
#pragma unroll
      for (int off = 1; off < 16; off <<= 1) {
        ss0 += __shfl_xor(ss0, off);
        ss1 += __shfl_xor(ss1, off);
      }
      float rr0 = rsqrtf(ss0 * (1.0f / 64.0f) + 1e-6f);
      float rr1 = rsqrtf(ss1 * (1.0f / 64.0f) + 1e-6f);
      float xn[8];
#pragma unroll
      for (int nt = 0; nt < 8; nt++)
        xn[nt] = acc[mt][nt][r] * ((nt < 4) ? rr0 : rr1) * gv[nt];
      int b = row >> 11, s = row & 2047;
      unsigned short* dst0 = (type == 0)
          ? Qn + ((size_t)(b * 32 + hb0) * 2048 + s) * 64
          : Kn + ((size_t)(b * 4 + hb0) * 2048 + s) * 64;
      unsigned short* dst1 = (type == 0)
          ? Qn + ((size_t)(b * 32 + hb0 + 1) * 2048 + s) * 64
          : Kn + ((size_t)(b * 4 + hb0 + 1) * 2048 + s) * 64;
#pragma unroll
      for (int nt = 0; nt < 8; nt++) {
        int d = (nt & 3) * 16 + l16;
        float rot = ((nt & 3) < 2) ? -xn[nt ^ 2] : xn[nt ^ 2];
        float cv = cosb[(size_t)row * 64 + d];
        float sv = sinb[(size_t)row * 64 + d];
        float val = (xn[nt] * cv + rot * sv) * scale;
        ((nt < 4) ? dst0 : dst1)[d] = f2bf(val);
      }
    }
}

// -------------------------------------------------------------- output GEMM
// grid 32 x 8 = 256 blocks; 2-blocks/CU capacity -> scheduler spreads 1/CU.
__global__ __launch_bounds__(256, 2) void gemm_out_k(
    const unsigned short* __restrict__ A, const unsigned short* __restrict__ W,
    float* __restrict__ C) {
  __shared__ __attribute__((aligned(16))) unsigned short lds[36864];  // 72 KB
  const int m0 = blockIdx.x * 128, n0 = blockIdx.y * 256;
  f32x4 acc[4][8];
  gemm_core(A, W, m0, n0, lds, acc);
  const int tid = threadIdx.x;
  const int w = tid >> 6, l = tid & 63, quad = l >> 4, l16 = l & 15;
  const int wm = (w & 1) * 64, wn = (w >> 1) * 128;
#pragma unroll
  for (int mt = 0; mt < 4; mt++)
#pragma unroll
    for (int nt = 0; nt < 8; nt++) {
      int row = m0 + wm + mt * 16 + quad * 4;
      int col = n0 + wn + nt * 16 + l16;
#pragma unroll
      for (int r = 0; r < 4; r++)
        C[(size_t)(row + r) * 2048 + col] = acc[mt][nt][r];
    }
}

// ---------------------------------------------------------- flash attention
// (unchanged from r10: r6 structure + setprio around MFMA clusters)
__global__ __launch_bounds__(256, 4) void attn(
    const unsigned short* __restrict__ Qn, const unsigned short* __restrict__ Kn,
    const unsigned short* __restrict__ Vt, const unsigned short* __restrict__ gate,
    unsigned short* __restrict__ act) {
  __shared__ __attribute__((aligned(16))) unsigned short smem[20480];  // 40 KB
  unsigned short* Ps = smem + 16384;    // 4 x [32 q][32 kv] = 8 KB

  const int tid = threadIdx.x, w = tid >> 6, l = tid & 63;
  const int quad = l >> 4, l16 = l & 15, l7 = l16 & 7;
  const int bh = blockIdx.y, b = bh >> 5, h = bh & 31, kvh = h >> 3;
  const int q0 = blockIdx.x * 128;

  const unsigned short* Qg = Qn + ((size_t)(b * 32 + h) * 2048 + q0) * 64;
  const unsigned short* Kg = Kn + (size_t)(b * 4 + kvh) * 2048 * 64;
  const unsigned short* Vg = Vt + (size_t)(b * 4 + kvh) * 64 * 2048;
  unsigned short* Pw = Ps + w * 1024;   // wave-private [32 q][32 kv]

  const int kq_src = ((tid & 7) ^ ((tid >> 3) & 7)) * 8;

  // ---- prologue: stage Q [128][64] into smem[0..8192), read q-fragments
#pragma unroll
  for (int i = 0; i < 4; i++)
    async16(smem + i * 2048 + tid * 8,
            Qg + (size_t)(i * 32 + (tid >> 3)) * 64 + kq_src);
  __syncthreads();
  bf16x8 qf[2][2];
#pragma unroll
  for (int mt = 0; mt < 2; mt++)
#pragma unroll
    for (int ks = 0; ks < 2; ks++) {
      int row = w * 32 + mt * 16 + l16;           // row&7 == l7
      qf[mt][ks] = *(const bf16x8*)&smem[row * 64 + ((ks * 4 + quad) ^ l7) * 8];
    }
  __syncthreads();   // Q region free for K/V staging

  const f32x4 Z4 = {0.f, 0.f, 0.f, 0.f};
  f32x4 O[2][4];
  float lp[2][4];
#pragma unroll
  for (int mt = 0; mt < 2; mt++) {
#pragma unroll
    for (int nt = 0; nt < 4; nt++) O[mt][nt] = Z4;
#pragma unroll
    for (int r = 0; r < 4; r++) lp[mt][r] = 0.f;
  }

  // stage tile 0 into buf0
#pragma unroll
  for (int i = 0; i < 2; i++) {
    async16(smem + i * 2048 + tid * 8,
            Kg + (size_t)(i * 32 + (tid >> 3)) * 64 + kq_src);
    async16(smem + 4096 + i * 2048 + tid * 8,
            Vg + (size_t)(i * 32 + (tid >> 3)) * 2048 + kq_src);
  }

  for (int kt = 0; kt < 32; kt++) {
    __syncthreads();   // drains stage(kt); all waves past compute(kt-1)

    if (kt < 31) {     // stage tile kt+1 into the other buffer (overlapped)
      unsigned short* nb = smem + ((kt + 1) & 1) * 8192;
      const int s1 = (kt + 1) * 64;
#pragma unroll
      for (int i = 0; i < 2; i++) {
        async16(nb + i * 2048 + tid * 8,
                Kg + (size_t)(s1 + i * 32 + (tid >> 3)) * 64 + kq_src);
        async16(nb + 4096 + i * 2048 + tid * 8,
                Vg + (size_t)(i * 32 + (tid >> 3)) * 2048 + s1 + kq_src);
      }
    }

    unsigned short* Ks  = smem + (kt & 1) * 8192;
    unsigned short* Vts = Ks + 4096;

    // ---- S = Q K^T over this kv-64 tile
    f32x4 sc[2][4];
#pragma unroll
    for (int mt = 0; mt < 2; mt++)
#pragma unroll
      for (int nt = 0; nt < 4; nt++) sc[mt][nt] = Z4;
    __builtin_amdgcn_s_setprio(1);
#pragma unroll
    for (int nt = 0; nt < 4; nt++) {
      int row = nt * 16 + l16;                    // row&7 == l7
      bf16x8 kf0 = *(const bf16x8*)&Ks[row * 64 + (quad ^ l7) * 8];
      bf16x8 kf1 = *(const bf16x8*)&Ks[row * 64 + ((4 + quad) ^ l7) * 8];
#pragma unroll
      for (int mt = 0; mt < 2; mt++) {
        sc[mt][nt] = __builtin_amdgcn_mfma_f32_16x16x32_bf16(qf[mt][0], kf0, sc[mt][nt], 0, 0, 0);
        sc[mt][nt] = __builtin_amdgcn_mfma_f32_16x16x32_bf16(qf[mt][1], kf1, sc[mt][nt], 0, 0, 0);
      }
    }
    __builtin_amdgcn_s_setprio(0);

    // ---- softmax + PV in two kv-32 sub-chunks through wave-private Ps
#pragma unroll
    for (int ks2 = 0; ks2 < 2; ks2++) {
#pragma unroll
      for (int mt = 0; mt < 2; mt++)
#pragma unroll
        for (int ntl = 0; ntl < 2; ntl++) {
          int nt = ks2 * 2 + ntl;
#pragma unroll
          for (int r = 0; r < 4; r++) {
            float p = __builtin_amdgcn_exp2f(sc[mt][nt][r]);
            union { float f; unsigned u; } x; x.f = p;
            union { unsigned u; float f; } t; t.u = x.u & 0xffff0000u;
            lp[mt][r] += t.f;
            int q = mt * 16 + quad * 4 + r;
            int c = ntl * 2 + (l16 >> 3);
            int phys = c ^ ((q >> 1) & 3);
            Pw[q * 32 + phys * 8 + l7] = (unsigned short)(x.u >> 16);
          }
        }
      lds_fence();   // P writes visible before reads (same wave)

      bf16x8 pf[2];
#pragma unroll
      for (int mt = 0; mt < 2; mt++) {
        int q = mt * 16 + l16;
        int phys = quad ^ ((l16 >> 1) & 3);
        pf[mt] = *(const bf16x8*)&Pw[q * 32 + phys * 8];
      }
      __builtin_amdgcn_s_setprio(1);
#pragma unroll
      for (int nt2 = 0; nt2 < 4; nt2++) {
        int d = nt2 * 16 + l16;                   // d&7 == l7
        bf16x8 vf = *(const bf16x8*)&Vts[d * 64 + ((ks2 * 4 + quad) ^ l7) * 8];
#pragma unroll
        for (int mt = 0; mt < 2; mt++)
          O[mt][nt2] = __builtin_amdgcn_mfma_f32_16x16x32_bf16(
              pf[mt], vf, O[mt][nt2], 0, 0, 0);
      }
      __builtin_amdgcn_s_setprio(0);
      lds_fence();   // sub-chunk reads retired before next sub-chunk writes
    }
  }

  // ---- final l reduction across the 16-lane column groups (once)
#pragma unroll
  for (int mt = 0; mt < 2; mt++)
#pragma unroll
    for (int r = 0; r < 4; r++) {
      float s = lp[mt][r];
#pragma unroll
      for (int off = 1; off < 16; off <<= 1) s += __shfl_xor(s, off);
      lp[mt][r] = s;
    }

  // ---- epilogue: O/l * sigmoid(gate) -> act[b][s][h*64+d]
#pragma unroll
  for (int mt = 0; mt < 2; mt++) {
    float inv[4];
#pragma unroll
    for (int r = 0; r < 4; r++) inv[r] = 1.0f / lp[mt][r];
#pragma unroll
    for (int nt = 0; nt < 4; nt++)
#pragma unroll
      for (int r = 0; r < 4; r++) {
        int srow = q0 + w * 32 + mt * 16 + quad * 4 + r;
        int col = h * 64 + nt * 16 + l16;
        size_t off = (size_t)(b * 2048 + srow) * 2048 + col;
        float g = bf2f(gate[off]);
        float sig = 1.0f / (1.0f + __builtin_amdgcn_exp2f(-g * LOG2E));
        act[off] = f2bf(O[mt][nt][r] * inv[r] * sig);
      }
  }
}

// ------------------------------------------------------------------ launcher
extern "C" void kernel_launch(void* const* d_in, const int* in_sizes, int n_in,
                              void* d_out, int out_size, void* d_ws, size_t ws_size,
                              hipStream_t stream) {
  const float* hid  = (const float*)d_in[0];
  const float* cosb = (const float*)d_in[1];
  const float* sinb = (const float*)d_in[2];
  const float* Wq   = (const float*)d_in[3];
  const float* Wk   = (const float*)d_in[4];
  const float* Wv   = (const float*)d_in[5];
  const float* Wg   = (const float*)d_in[6];
  const float* Wo   = (const float*)d_in[7];
  const float* qg   = (const float*)d_in[8];
  const float* kg   = (const float*)d_in[9];
  float* out = (float*)d_out;

  char* ws = (char*)d_ws;
  unsigned short* Xb   = (unsigned short*)(ws);              // 16,777,216 B
  unsigned short* WqB  = (unsigned short*)(ws + 16777216);   //  8,388,608
  unsigned short* WkB  = (unsigned short*)(ws + 25165824);   //  1,048,576
  unsigned short* WvB  = (unsigned short*)(ws + 26214400);   //  1,048,576
  unsigned short* WgB  = (unsigned short*)(ws + 27262976);   //  8,388,608
  unsigned short* WoB  = (unsigned short*)(ws + 35651584);   //  8,388,608
  unsigned short* gate = (unsigned short*)(ws + 44040192);   // 16,777,216
  unsigned short* Qn   = (unsigned short*)(ws + 60817408);   // 16,777,216
  unsigned short* Kn   = (unsigned short*)(ws + 77594624);   //  2,097,152
  unsigned short* Vt   = (unsigned short*)(ws + 79691776);   //  2,097,152
  // region reuse: act overlays WqB..WgB (18 MB, dead after gemm_qkvg)
  unsigned short* act = WqB;

  cvt_all<<<dim3(2048), dim3(256), 0, stream>>>(
      hid, Wq, Wk, Wv, Wg, Wo, Xb, WqB, WkB, WvB, WgB, WoB);

  gemm_qkvg<<<dim3(32, 18), dim3(256), 0, stream>>>(
      Xb, WqB, WkB, WvB, WgB, cosb, sinb, qg, kg, Qn, Kn, Vt, gate);

  attn<<<dim3(16, 64), dim3(256), 0, stream>>>(Qn, Kn, Vt, gate, act);

  gemm_out_k<<<dim3(32, 8), dim3(256), 0, stream>>>(act, WoB, out);
}

// Round 10
// 378.159 us; speedup vs baseline: 1.0353x; 1.0111x over previous
//
#include <hip/hip_runtime.h>

// AfmoeAttention on MI355X (gfx950), round 16.
// r8-r15: six qkvg core variants all ~113-116us / MfmaUtil 28%. The clue:
// gemm_out_k (SAME core, 256/512-block grid = integer blocks/CU, single
// round) runs at ~800 TF-effective vs qkvg's 672. The invariant was the
// DISPATCH SHAPE: 576 blocks at 2/CU -> 64 CUs carry 3 blocks, 192 carry 2
// -> 75% packing efficiency + straggler tail.
// r16: granular balanced grid. BM=128 BN=128, 2 waves/block (128 thr),
// per-wave 64x128 (r15 acc[4][8] shape), dbuf 32KB LDS -> 5 blocks/CU cap.
//   qkvg: 32x36 = 1152 blocks -> 4.5/CU (imbalance 1.11 vs 1.33)
//   out:  32x16 =  512 blocks -> exactly 2/CU, perfectly balanced
// Loop = m97-proven dbuf: stage(t+1) -> reads+MFMAs one section ->
// vmcnt(0) -> barrier; 5-way co-residency de-syncs the drains.
// Swizzle unchanged (chunk ^ ((row>>1)&3), measured 0 conflicts).
// attn + cvt_all unchanged.

#define LOG2E 1.44269504088896340736f

typedef __attribute__((ext_vector_type(4))) float f32x4;
typedef __attribute__((ext_vector_type(8))) short bf16x8;   // 8 x bf16 (4 VGPRs)

__device__ __forceinline__ float bf2f(unsigned short u) {
  union { unsigned u; float f; } x; x.u = ((unsigned)u) << 16; return x.f;
}
__device__ __forceinline__ unsigned short f2bf(float f) {
  union { float f; unsigned u; } x; x.f = f;
  unsigned r = x.u + 0x7fffu + ((x.u >> 16) & 1u);   // RNE
  return (unsigned short)(r >> 16);
}

// async global->LDS, 16B per lane. LDS dest = wave-uniform base + lane*16.
__device__ __forceinline__ void async16(void* lds, const void* g) {
  __builtin_amdgcn_global_load_lds(
      (const __attribute__((address_space(1))) unsigned*)g,
      (__attribute__((address_space(3))) unsigned*)lds, 16, 0, 0);
}
__device__ __forceinline__ void lds_fence() {
  __asm__ volatile("s_waitcnt lgkmcnt(0)" ::: "memory");
}

// ---------------------------------------------------------- fused cvt kernel
__global__ __launch_bounds__(256) void cvt_all(
    const float* __restrict__ s0, const float* __restrict__ s1,
    const float* __restrict__ s2, const float* __restrict__ s3,
    const float* __restrict__ s4, const float* __restrict__ s5,
    unsigned short* __restrict__ d0, unsigned short* __restrict__ d1,
    unsigned short* __restrict__ d2, unsigned short* __restrict__ d3,
    unsigned short* __restrict__ d4, unsigned short* __restrict__ d5) {
  const long total = 5505024;                       // f4 elements overall
  const long stride = (long)gridDim.x * 256;
  for (long i = (long)blockIdx.x * 256 + threadIdx.x; i < total; i += stride) {
    const float* s; unsigned short* d; long off;
    if      (i < 2097152) { s = s0; d = d0; off = 0; }
    else if (i < 3145728) { s = s1; d = d1; off = 2097152; }
    else if (i < 3276800) { s = s2; d = d2; off = 3145728; }
    else if (i < 3407872) { s = s3; d = d3; off = 3276800; }
    else if (i < 4456448) { s = s4; d = d4; off = 3407872; }
    else                  { s = s5; d = d5; off = 4456448; }
    long j = i - off;
    float4 v = reinterpret_cast<const float4*>(s)[j];
    ushort4 u;
    u.x = f2bf(v.x); u.y = f2bf(v.y); u.z = f2bf(v.z); u.w = f2bf(v.w);
    reinterpret_cast<ushort4*>(d)[j] = u;
  }
}

// --------------------------- 128x128 core, 2 waves, per-wave 64x128
// BK=32. Wave w (0/1): rows w*64..+64, all 128 cols -> acc[4][8] 16x16 frags
// (12 frag ds_read_b128 feed 32 MFMAs/iter/wave).
// LDS row = 32 bf16 = 4 chunks of 16B; logical chunk c of row r at phys
// c ^ ((r>>1)&3); staging pre-swizzles the GLOBAL source chunk (rows +32
// keep (r>>1)&3 since 16%4==0).
// LDS: dbuf 2 x {A 4096 shorts, B 4096 shorts} = 32 KB -> 5 blocks/CU cap.
// Iter t: stage(t+1) (8 loads/thread), frag reads + MFMAs in one section
// (compiler emits counted lgkmcnt), vmcnt(0), barrier.
__device__ __forceinline__ void gemm_core(
    const unsigned short* __restrict__ A, const unsigned short* __restrict__ W,
    int m0, int n0, unsigned short* lds, f32x4 acc[4][8]) {
  const int tid = threadIdx.x;              // 0..127
  const int w = tid >> 6, l = tid & 63, quad = l >> 4, l16 = l & 15;
  const int wm = w * 64;
  const int rlo = tid >> 2, ch = tid & 3;   // stage: row 0..31, chunk 0..3

  const f32x4 Z4 = {0.f, 0.f, 0.f, 0.f};
#pragma unroll
  for (int i = 0; i < 4; i++)
#pragma unroll
    for (int j = 0; j < 8; j++) acc[i][j] = Z4;

  // staging sources, pre-swizzled chunk
  const unsigned short* gA =
      A + (size_t)(m0 + rlo) * 2048 + ((ch ^ ((rlo >> 1) & 3)) * 8);
  const unsigned short* gB =
      W + (size_t)(n0 + rlo) * 2048 + ((ch ^ ((rlo >> 1) & 3)) * 8);

  int arow[4], brow[8];
#pragma unroll
  for (int mt = 0; mt < 4; mt++) arow[mt] = (wm + mt * 16 + l16) * 32;
#pragma unroll
  for (int nt = 0; nt < 8; nt++) brow[nt] = (nt * 16 + l16) * 32;
  const int fx = (quad ^ ((l16 >> 1) & 3)) * 8;

  // ---- prologue: stage tile 0 -> buf0 (8 loads/thread)
#pragma unroll
  for (int p = 0; p < 4; p++) {
    async16(lds + p * 1024 + tid * 8,        gA + (size_t)p * 32 * 2048);
    async16(lds + 4096 + p * 1024 + tid * 8, gB + (size_t)p * 32 * 2048);
  }
  __asm__ volatile("s_waitcnt vmcnt(0)" ::: "memory");
  __builtin_amdgcn_s_barrier();

  for (int t = 0; t < 64; ++t) {
    unsigned short* cbuf = lds + (t & 1) * 8192;

    if (t < 63) {                           // stage tile t+1 (8 loads)
      unsigned short* nbuf = lds + ((t + 1) & 1) * 8192;
      const int ko = (t + 1) * 32;
#pragma unroll
      for (int p = 0; p < 4; p++) {
        async16(nbuf + p * 1024 + tid * 8,
                gA + (size_t)p * 32 * 2048 + ko);
        async16(nbuf + 4096 + p * 1024 + tid * 8,
                gB + (size_t)p * 32 * 2048 + ko);
      }
    }

    // frag reads + MFMAs in one section: compiler interleaves with counted
    // lgkmcnt so read latency hides under MFMA columns.
    bf16x8 af[4], bf[8];
#pragma unroll
    for (int mt = 0; mt < 4; mt++)
      af[mt] = *(const bf16x8*)&cbuf[arow[mt] + fx];
#pragma unroll
    for (int nt = 0; nt < 8; nt++)
      bf[nt] = *(const bf16x8*)&cbuf[4096 + brow[nt] + fx];

    __builtin_amdgcn_s_setprio(1);
#pragma unroll
    for (int nt = 0; nt < 8; nt++)
#pragma unroll
      for (int mt = 0; mt < 4; mt++)
        acc[mt][nt] = __builtin_amdgcn_mfma_f32_16x16x32_bf16(
            af[mt], bf[nt], acc[mt][nt], 0, 0, 0);
    __builtin_amdgcn_s_setprio(0);

    __asm__ volatile("s_waitcnt vmcnt(0)" ::: "memory");  // stage(t+1) landed
    __builtin_amdgcn_s_barrier();           // buf[t] reads done block-wide
  }
}

// --------------------------------------- fused QKVG GEMM + RMSNorm/RoPE/T
// 128-col tiles (ny 0..35): ny 0..15 Q | 16..17 K | 18..19 V | 20..35 G.
// Each block spans 128 cols = TWO heads (nt 0..3 head hb0, nt 4..7 hb0+1).
__global__ __launch_bounds__(128, 2) void gemm_qkvg(
    const unsigned short* __restrict__ X,
    const unsigned short* __restrict__ Wq, const unsigned short* __restrict__ Wk,
    const unsigned short* __restrict__ Wv, const unsigned short* __restrict__ Wg,
    const float* __restrict__ cosb, const float* __restrict__ sinb,
    const float* __restrict__ qg, const float* __restrict__ kg,
    unsigned short* __restrict__ Qn, unsigned short* __restrict__ Kn,
    unsigned short* __restrict__ Vt, unsigned short* __restrict__ gate) {
  __shared__ __attribute__((aligned(16))) unsigned short lds[16384];  // 32 KB
  const int ny = blockIdx.y;
  const unsigned short* W; int n0, type;
  if (ny < 16)      { W = Wq; n0 = ny * 128;        type = 0; }
  else if (ny < 18) { W = Wk; n0 = (ny - 16) * 128; type = 1; }
  else if (ny < 20) { W = Wv; n0 = (ny - 18) * 128; type = 2; }
  else              { W = Wg; n0 = (ny - 20) * 128; type = 3; }
  const int m0 = blockIdx.x * 128;

  f32x4 acc[4][8];
  gemm_core(X, W, m0, n0, lds, acc);

  const int tid = threadIdx.x;
  const int w = tid >> 6, l = tid & 63, quad = l >> 4, l16 = l & 15;
  const int wm = w * 64;

  if (type == 3) {          // gate: plain bf16 store
#pragma unroll
    for (int mt = 0; mt < 4; mt++)
#pragma unroll
      for (int r = 0; r < 4; r++) {
        int row = m0 + wm + mt * 16 + quad * 4 + r;
#pragma unroll
        for (int nt = 0; nt < 8; nt++)
          gate[(size_t)row * 2048 + n0 + nt * 16 + l16] =
              f2bf(acc[mt][nt][r]);
      }
    return;
  }
  if (type == 2) {          // V: transpose-scatter to Vt[b][kv][d][s]
#pragma unroll
    for (int mt = 0; mt < 4; mt++)
#pragma unroll
      for (int r = 0; r < 4; r++) {
        int row = m0 + wm + mt * 16 + quad * 4 + r;
        int b = row >> 11, s = row & 2047;
#pragma unroll
        for (int nt = 0; nt < 8; nt++) {
          int col = n0 + nt * 16 + l16;
          int kvh = col >> 6, d = col & 63;
          Vt[((size_t)(b * 4 + kvh) * 64 + d) * 2048 + s] =
              f2bf(acc[mt][nt][r]);
        }
      }
    return;
  }

  // Q/K: RMSNorm (f32 acc) + RoPE + scale, transposed store. Two heads/block.
  const float* gamma = (type == 0) ? qg : kg;
  const float scale  = (type == 0) ? 0.125f : LOG2E;
  const int hb0 = n0 >> 6;           // first head of this block's 128 cols
  float gv[8];
#pragma unroll
  for (int nt = 0; nt < 8; nt++) gv[nt] = gamma[(nt & 3) * 16 + l16];

#pragma unroll
  for (int mt = 0; mt < 4; mt++)
#pragma unroll
    for (int r = 0; r < 4; r++) {
      int row = m0 + wm + mt * 16 + quad * 4 + r;
      float ss0 = 0.f, ss1 = 0.f;
#pragma unroll
      for (int nt = 0; nt < 4; nt++) {
        float v = acc[mt][nt][r]; ss0 += v * v;
      }
#pragma unroll
      for (int nt = 4; nt < 8; nt++) {
        float v = acc[mt][nt][r]; ss1 += v * v;
      }
#pragma unroll
      for (int off = 1; off < 16; off <<= 1) {
        ss0 += __shfl_xor(ss0, off);
        ss1 += __shfl_xor(ss1, off);
      }
      float rr0 = rsqrtf(ss0 * (1.0f / 64.0f) + 1e-6f);
      float rr1 = rsqrtf(ss1 * (1.0f / 64.0f) + 1e-6f);
      float xn[8];
#pragma unroll
      for (int nt = 0; nt < 8; nt++)
        xn[nt] = acc[mt][nt][r] * ((nt < 4) ? rr0 : rr1) * gv[nt];
      int b = row >> 11, s = row & 2047;
      unsigned short* dst0 = (type == 0)
          ? Qn + ((size_t)(b * 32 + hb0) * 2048 + s) * 64
          : Kn + ((size_t)(b * 4 + hb0) * 2048 + s) * 64;
      unsigned short* dst1 = (type == 0)
          ? Qn + ((size_t)(b * 32 + hb0 + 1) * 2048 + s) * 64
          : Kn + ((size_t)(b * 4 + hb0 + 1) * 2048 + s) * 64;
#pragma unroll
      for (int nt = 0; nt < 8; nt++) {
        int d = (nt & 3) * 16 + l16;
        float rot = ((nt & 3) < 2) ? -xn[nt ^ 2] : xn[nt ^ 2];
        float cv = cosb[(size_t)row * 64 + d];
        float sv = sinb[(size_t)row * 64 + d];
        float val = (xn[nt] * cv + rot * sv) * scale;
        ((nt < 4) ? dst0 : dst1)[d] = f2bf(val);
      }
    }
}

// -------------------------------------------------------------- output GEMM
// grid 32 x 16 = 512 blocks = exactly 2 blocks/CU, perfectly balanced.
__global__ __launch_bounds__(128, 2) void gemm_out_k(
    const unsigned short* __restrict__ A, const unsigned short* __restrict__ W,
    float* __restrict__ C) {
  __shared__ __attribute__((aligned(16))) unsigned short lds[16384];  // 32 KB
  const int m0 = blockIdx.x * 128, n0 = blockIdx.y * 128;
  f32x4 acc[4][8];
  gemm_core(A, W, m0, n0, lds, acc);
  const int tid = threadIdx.x;
  const int w = tid >> 6, l = tid & 63, quad = l >> 4, l16 = l & 15;
  const int wm = w * 64;
#pragma unroll
  for (int mt = 0; mt < 4; mt++)
#pragma unroll
    for (int nt = 0; nt < 8; nt++) {
      int row = m0 + wm + mt * 16 + quad * 4;
      int col = n0 + nt * 16 + l16;
#pragma unroll
      for (int r = 0; r < 4; r++)
        C[(size_t)(row + r) * 2048 + col] = acc[mt][nt][r];
    }
}

// ---------------------------------------------------------- flash attention
// (unchanged from r10: r6 structure + setprio around MFMA clusters)
__global__ __launch_bounds__(256, 4) void attn(
    const unsigned short* __restrict__ Qn, const unsigned short* __restrict__ Kn,
    const unsigned short* __restrict__ Vt, const unsigned short* __restrict__ gate,
    unsigned short* __restrict__ act) {
  __shared__ __attribute__((aligned(16))) unsigned short smem[20480];  // 40 KB
  unsigned short* Ps = smem + 16384;    // 4 x [32 q][32 kv] = 8 KB

  const int tid = threadIdx.x, w = tid >> 6, l = tid & 63;
  const int quad = l >> 4, l16 = l & 15, l7 = l16 & 7;
  const int bh = blockIdx.y, b = bh >> 5, h = bh & 31, kvh = h >> 3;
  const int q0 = blockIdx.x * 128;

  const unsigned short* Qg = Qn + ((size_t)(b * 32 + h) * 2048 + q0) * 64;
  const unsigned short* Kg = Kn + (size_t)(b * 4 + kvh) * 2048 * 64;
  const unsigned short* Vg = Vt + (size_t)(b * 4 + kvh) * 64 * 2048;
  unsigned short* Pw = Ps + w * 1024;   // wave-private [32 q][32 kv]

  const int kq_src = ((tid & 7) ^ ((tid >> 3) & 7)) * 8;

  // ---- prologue: stage Q [128][64] into smem[0..8192), read q-fragments
#pragma unroll
  for (int i = 0; i < 4; i++)
    async16(smem + i * 2048 + tid * 8,
            Qg + (size_t)(i * 32 + (tid >> 3)) * 64 + kq_src);
  __syncthreads();
  bf16x8 qf[2][2];
#pragma unroll
  for (int mt = 0; mt < 2; mt++)
#pragma unroll
    for (int ks = 0; ks < 2; ks++) {
      int row = w * 32 + mt * 16 + l16;           // row&7 == l7
      qf[mt][ks] = *(const bf16x8*)&smem[row * 64 + ((ks * 4 + quad) ^ l7) * 8];
    }
  __syncthreads();   // Q region free for K/V staging

  const f32x4 Z4 = {0.f, 0.f, 0.f, 0.f};
  f32x4 O[2][4];
  float lp[2][4];
#pragma unroll
  for (int mt = 0; mt < 2; mt++) {
#pragma unroll
    for (int nt = 0; nt < 4; nt++) O[mt][nt] = Z4;
#pragma unroll
    for (int r = 0; r < 4; r++) lp[mt][r] = 0.f;
  }

  // stage tile 0 into buf0
#pragma unroll
  for (int i = 0; i < 2; i++) {
    async16(smem + i * 2048 + tid * 8,
            Kg + (size_t)(i * 32 + (tid >> 3)) * 64 + kq_src);
    async16(smem + 4096 + i * 2048 + tid * 8,
            Vg + (size_t)(i * 32 + (tid >> 3)) * 2048 + kq_src);
  }

  for (int kt = 0; kt < 32; kt++) {
    __syncthreads();   // drains stage(kt); all waves past compute(kt-1)

    if (kt < 31) {     // stage tile kt+1 into the other buffer (overlapped)
      unsigned short* nb = smem + ((kt + 1) & 1) * 8192;
      const int s1 = (kt + 1) * 64;
#pragma unroll
      for (int i = 0; i < 2; i++) {
        async16(nb + i * 2048 + tid * 8,
                Kg + (size_t)(s1 + i * 32 + (tid >> 3)) * 64 + kq_src);
        async16(nb + 4096 + i * 2048 + tid * 8,
                Vg + (size_t)(i * 32 + (tid >> 3)) * 2048 + s1 + kq_src);
      }
    }

    unsigned short* Ks  = smem + (kt & 1) * 8192;
    unsigned short* Vts = Ks + 4096;

    // ---- S = Q K^T over this kv-64 tile
    f32x4 sc[2][4];
#pragma unroll
    for (int mt = 0; mt < 2; mt++)
#pragma unroll
      for (int nt = 0; nt < 4; nt++) sc[mt][nt] = Z4;
    __builtin_amdgcn_s_setprio(1);
#pragma unroll
    for (int nt = 0; nt < 4; nt++) {
      int row = nt * 16 + l16;                    // row&7 == l7
      bf16x8 kf0 = *(const bf16x8*)&Ks[row * 64 + (quad ^ l7) * 8];
      bf16x8 kf1 = *(const bf16x8*)&Ks[row * 64 + ((4 + quad) ^ l7) * 8];
#pragma unroll
      for (int mt = 0; mt < 2; mt++) {
        sc[mt][nt] = __builtin_amdgcn_mfma_f32_16x16x32_bf16(qf[mt][0], kf0, sc[mt][nt], 0, 0, 0);
        sc[mt][nt] = __builtin_amdgcn_mfma_f32_16x16x32_bf16(qf[mt][1], kf1, sc[mt][nt], 0, 0, 0);
      }
    }
    __builtin_amdgcn_s_setprio(0);

    // ---- softmax + PV in two kv-32 sub-chunks through wave-private Ps
#pragma unroll
    for (int ks2 = 0; ks2 < 2; ks2++) {
#pragma unroll
      for (int mt = 0; mt < 2; mt++)
#pragma unroll
        for (int ntl = 0; ntl < 2; ntl++) {
          int nt = ks2 * 2 + ntl;
#pragma unroll
          for (int r = 0; r < 4; r++) {
            float p = __builtin_amdgcn_exp2f(sc[mt][nt][r]);
            union { float f; unsigned u; } x; x.f = p;
            union { unsigned u; float f; } t; t.u = x.u & 0xffff0000u;
            lp[mt][r] += t.f;
            int q = mt * 16 + quad * 4 + r;
            int c = ntl * 2 + (l16 >> 3);
            int phys = c ^ ((q >> 1) & 3);
            Pw[q * 32 + phys * 8 + l7] = (unsigned short)(x.u >> 16);
          }
        }
      lds_fence();   // P writes visible before reads (same wave)

      bf16x8 pf[2];
#pragma unroll
      for (int mt = 0; mt < 2; mt++) {
        int q = mt * 16 + l16;
        int phys = quad ^ ((l16 >> 1) & 3);
        pf[mt] = *(const bf16x8*)&Pw[q * 32 + phys * 8];
      }
      __builtin_amdgcn_s_setprio(1);
#pragma unroll
      for (int nt2 = 0; nt2 < 4; nt2++) {
        int d = nt2 * 16 + l16;                   // d&7 == l7
        bf16x8 vf = *(const bf16x8*)&Vts[d * 64 + ((ks2 * 4 + quad) ^ l7) * 8];
#pragma unroll
        for (int mt = 0; mt < 2; mt++)
          O[mt][nt2] = __builtin_amdgcn_mfma_f32_16x16x32_bf16(
              pf[mt], vf, O[mt][nt2], 0, 0, 0);
      }
      __builtin_amdgcn_s_setprio(0);
      lds_fence();   // sub-chunk reads retired before next sub-chunk writes
    }
  }

  // ---- final l reduction across the 16-lane column groups (once)
#pragma unroll
  for (int mt = 0; mt < 2; mt++)
#pragma unroll
    for (int r = 0; r < 4; r++) {
      float s = lp[mt][r];
#pragma unroll
      for (int off = 1; off < 16; off <<= 1) s += __shfl_xor(s, off);
      lp[mt][r] = s;
    }

  // ---- epilogue: O/l * sigmoid(gate) -> act[b][s][h*64+d]
#pragma unroll
  for (int mt = 0; mt < 2; mt++) {
    float inv[4];
#pragma unroll
    for (int r = 0; r < 4; r++) inv[r] = 1.0f / lp[mt][r];
#pragma unroll
    for (int nt = 0; nt < 4; nt++)
#pragma unroll
      for (int r = 0; r < 4; r++) {
        int srow = q0 + w * 32 + mt * 16 + quad * 4 + r;
        int col = h * 64 + nt * 16 + l16;
        size_t off = (size_t)(b * 2048 + srow) * 2048 + col;
        float g = bf2f(gate[off]);
        float sig = 1.0f / (1.0f + __builtin_amdgcn_exp2f(-g * LOG2E));
        act[off] = f2bf(O[mt][nt][r] * inv[r] * sig);
      }
  }
}

// ------------------------------------------------------------------ launcher
extern "C" void kernel_launch(void* const* d_in, const int* in_sizes, int n_in,
                              void* d_out, int out_size, void* d_ws, size_t ws_size,
                              hipStream_t stream) {
  const float* hid  = (const float*)d_in[0];
  const float* cosb = (const float*)d_in[1];
  const float* sinb = (const float*)d_in[2];
  const float* Wq   = (const float*)d_in[3];
  const float* Wk   = (const float*)d_in[4];
  const float* Wv   = (const float*)d_in[5];
  const float* Wg   = (const float*)d_in[6];
  const float* Wo   = (const float*)d_in[7];
  const float* qg   = (const float*)d_in[8];
  const float* kg   = (const float*)d_in[9];
  float* out = (float*)d_out;

  char* ws = (char*)d_ws;
  unsigned short* Xb   = (unsigned short*)(ws);              // 16,777,216 B
  unsigned short* WqB  = (unsigned short*)(ws + 16777216);   //  8,388,608
  unsigned short* WkB  = (unsigned short*)(ws + 25165824);   //  1,048,576
  unsigned short* WvB  = (unsigned short*)(ws + 26214400);   //  1,048,576
  unsigned short* WgB  = (unsigned short*)(ws + 27262976);   //  8,388,608
  unsigned short* WoB  = (unsigned short*)(ws + 35651584);   //  8,388,608
  unsigned short* gate = (unsigned short*)(ws + 44040192);   // 16,777,216
  unsigned short* Qn   = (unsigned short*)(ws + 60817408);   // 16,777,216
  unsigned short* Kn   = (unsigned short*)(ws + 77594624);   //  2,097,152
  unsigned short* Vt   = (unsigned short*)(ws + 79691776);   //  2,097,152
  // region reuse: act overlays WqB..WgB (18 MB, dead after gemm_qkvg)
  unsigned short* act = WqB;

  cvt_all<<<dim3(2048), dim3(256), 0, stream>>>(
      hid, Wq, Wk, Wv, Wg, Wo, Xb, WqB, WkB, WvB, WgB, WoB);

  gemm_qkvg<<<dim3(32, 36), dim3(128), 0, stream>>>(
      Xb, WqB, WkB, WvB, WgB, cosb, sinb, qg, kg, Qn, Kn, Vt, gate);

  attn<<<dim3(16, 64), dim3(256), 0, stream>>>(Qn, Kn, Vt, gate, act);

  gemm_out_k<<<dim3(32, 16), dim3(128), 0, stream>>>(act, WoB, out);
}